// Round 1
// baseline (1439.164 us; speedup 1.0000x reference)
//
#include <hip/hip_runtime.h>
#include <hip/hip_bf16.h>

// ---------------------------------------------------------------------------
// BasicCountNet: two GINs (query 64n/512e, data 50000n/600000e) + MLP head.
// Round 1: correctness baseline.
//   - edge aggregation: s = x; atomicAdd scatter of x[src] into s[dst]
//   - GEMMs: fp32 tiled (16 rows x 256 cols per 256-thread block), LDS A-tile
//   - column-sum pooling, single-block MLP head
// ---------------------------------------------------------------------------

#define NQ 64
#define EQ 512
#define ND 50000
#define ED 600000
#define FDIM 128
#define HDIM 256

// C[N,256] = act(A[N,K] @ W[K,256] + b)
template <int K>
__global__ void gemm_bias_act(const float* __restrict__ A,
                              const float* __restrict__ W,
                              const float* __restrict__ b,
                              float* __restrict__ C,
                              int N, int relu) {
    __shared__ float As[16 * K];
    const int row0 = blockIdx.x * 16;
    const float* Ab = A + (size_t)row0 * K;
    for (int i = threadIdx.x; i < 16 * K; i += 256) As[i] = Ab[i];
    __syncthreads();

    const int c = threadIdx.x;  // output column 0..255
    float acc[16];
#pragma unroll
    for (int r = 0; r < 16; ++r) acc[r] = 0.f;

    for (int k = 0; k < K; ++k) {
        const float wv = W[(size_t)k * 256 + c];
#pragma unroll
        for (int r = 0; r < 16; ++r) acc[r] += As[r * K + k] * wv;
    }

    const float bias = b[c];
#pragma unroll
    for (int r = 0; r < 16; ++r) {
        float v = acc[r] + bias;
        if (relu) v = fmaxf(v, 0.f);
        C[(size_t)(row0 + r) * 256 + c] = v;
    }
}

// s[dst[e]*F + f] += x[src[e]*F + f]   (F = 1<<logF)
__global__ void scatter_add_edges(const float* __restrict__ x,
                                  float* __restrict__ s,
                                  const int* __restrict__ src,
                                  const int* __restrict__ dst,
                                  long long total, int logF) {
    long long idx = (long long)blockIdx.x * blockDim.x + threadIdx.x;
    if (idx >= total) return;
    const int F1 = (1 << logF) - 1;
    const int e = (int)(idx >> logF);
    const int f = (int)(idx & F1);
    const int sn = src[e];
    const int dn = dst[e];
    atomicAdd(&s[((size_t)dn << logF) + f], x[((size_t)sn << logF) + f]);
}

// out[t] += sum_rows X[r][t]  (256 features)
__global__ void colsum256(const float* __restrict__ X, float* __restrict__ out, int N) {
    const int t = threadIdx.x;
    const int r0 = blockIdx.x * 256;
    const int rend = (r0 + 256 < N) ? (r0 + 256) : N;
    float acc = 0.f;
    for (int r = r0; r < rend; ++r) acc += X[(size_t)r * 256 + t];
    atomicAdd(&out[t], acc);
}

__global__ void mlp_head(const float* __restrict__ pooled,
                         const float* __restrict__ lW1, const float* __restrict__ lb1,
                         const float* __restrict__ lW2, const float* __restrict__ lb2,
                         const float* __restrict__ lW3, const float* __restrict__ lb3,
                         float* __restrict__ out) {
    __shared__ float h0[512];
    __shared__ float h1[256];
    __shared__ float h2[128];
    const int t = threadIdx.x;  // 256 threads
    h0[t] = pooled[t];
    h0[t + 256] = pooled[t + 256];
    __syncthreads();

    float acc = lb1[t];
    for (int k = 0; k < 512; ++k) acc += h0[k] * lW1[k * 256 + t];
    h1[t] = fmaxf(acc, 0.f);
    __syncthreads();

    if (t < 128) {
        float a = lb2[t];
        for (int k = 0; k < 256; ++k) a += h1[k] * lW2[k * 128 + t];
        h2[t] = fmaxf(a, 0.f);
    }
    __syncthreads();

    if (t < 8) {
        float a = lb3[t];
        for (int k = 0; k < 128; ++k) a += h2[k] * lW3[k * 8 + t];
        out[t] = fmaxf(a, 0.f);
    }
}

extern "C" void kernel_launch(void* const* d_in, const int* in_sizes, int n_in,
                              void* d_out, int out_size, void* d_ws, size_t ws_size,
                              hipStream_t stream) {
    const float* q_x  = (const float*)d_in[0];   // [64,128]
    const float* d_x  = (const float*)d_in[1];   // [50000,128]
    const int*   q_el = (const int*)d_in[2];     // [2,512]
    const int*   d_el = (const int*)d_in[3];     // [2,600000]
    const float* qW1 = (const float*)d_in[4];  const float* qb1 = (const float*)d_in[5];
    const float* qW2 = (const float*)d_in[6];  const float* qb2 = (const float*)d_in[7];
    const float* qW3 = (const float*)d_in[8];  const float* qb3 = (const float*)d_in[9];
    const float* qW4 = (const float*)d_in[10]; const float* qb4 = (const float*)d_in[11];
    const float* dW1 = (const float*)d_in[12]; const float* db1 = (const float*)d_in[13];
    const float* dW2 = (const float*)d_in[14]; const float* db2 = (const float*)d_in[15];
    const float* dW3 = (const float*)d_in[16]; const float* db3 = (const float*)d_in[17];
    const float* dW4 = (const float*)d_in[18]; const float* db4 = (const float*)d_in[19];
    const float* lW1 = (const float*)d_in[20]; const float* lb1 = (const float*)d_in[21];
    const float* lW2 = (const float*)d_in[22]; const float* lb2 = (const float*)d_in[23];
    const float* lW3 = (const float*)d_in[24]; const float* lb3 = (const float*)d_in[25];

    const int* q_src = q_el;            const int* q_dst = q_el + EQ;
    const int* d_src = d_el;            const int* d_dst = d_el + ED;

    // workspace layout (floats)
    float* ws = (float*)d_ws;
    size_t o = 0;
    float* qs1 = ws + o; o += (size_t)NQ * FDIM;   // conv1 sum (query)
    float* qt2 = ws + o; o += (size_t)NQ * HDIM;   // h1 / s2
    float* qt3 = ws + o; o += (size_t)NQ * HDIM;   // h / y
    float* qt4 = ws + o; o += (size_t)NQ * HDIM;   // h2
    float* ds1 = ws + o; o += (size_t)ND * FDIM;
    float* dt2 = ws + o; o += (size_t)ND * HDIM;
    float* dt3 = ws + o; o += (size_t)ND * HDIM;
    float* dt4 = ws + o; o += (size_t)ND * HDIM;
    float* pooled = ws + o; o += 512;
    (void)ws_size; (void)n_in; (void)in_sizes; (void)out_size;

    hipMemsetAsync(pooled, 0, 512 * sizeof(float), stream);

    // ---------------- query graph ----------------
    hipMemcpyAsync(qs1, q_x, (size_t)NQ * FDIM * sizeof(float),
                   hipMemcpyDeviceToDevice, stream);
    {
        long long total = (long long)EQ * FDIM;
        int blocks = (int)((total + 255) / 256);
        scatter_add_edges<<<blocks, 256, 0, stream>>>(q_x, qs1, q_src, q_dst, total, 7);
    }
    gemm_bias_act<FDIM><<<NQ / 16, 256, 0, stream>>>(qs1, qW1, qb1, qt2, NQ, 1);
    gemm_bias_act<HDIM><<<NQ / 16, 256, 0, stream>>>(qt2, qW2, qb2, qt3, NQ, 1); // fused inter-conv ReLU
    hipMemcpyAsync(qt2, qt3, (size_t)NQ * HDIM * sizeof(float),
                   hipMemcpyDeviceToDevice, stream);
    {
        long long total = (long long)EQ * HDIM;
        int blocks = (int)((total + 255) / 256);
        scatter_add_edges<<<blocks, 256, 0, stream>>>(qt3, qt2, q_src, q_dst, total, 8);
    }
    gemm_bias_act<HDIM><<<NQ / 16, 256, 0, stream>>>(qt2, qW3, qb3, qt4, NQ, 1);
    gemm_bias_act<HDIM><<<NQ / 16, 256, 0, stream>>>(qt4, qW4, qb4, qt3, NQ, 0);
    colsum256<<<(NQ + 255) / 256, 256, 0, stream>>>(qt3, pooled, NQ);

    // ---------------- data graph ----------------
    hipMemcpyAsync(ds1, d_x, (size_t)ND * FDIM * sizeof(float),
                   hipMemcpyDeviceToDevice, stream);
    {
        long long total = (long long)ED * FDIM;
        int blocks = (int)((total + 255) / 256);
        scatter_add_edges<<<blocks, 256, 0, stream>>>(d_x, ds1, d_src, d_dst, total, 7);
    }
    gemm_bias_act<FDIM><<<(ND + 15) / 16, 256, 0, stream>>>(ds1, dW1, db1, dt2, ND, 1);
    gemm_bias_act<HDIM><<<(ND + 15) / 16, 256, 0, stream>>>(dt2, dW2, db2, dt3, ND, 1);
    hipMemcpyAsync(dt2, dt3, (size_t)ND * HDIM * sizeof(float),
                   hipMemcpyDeviceToDevice, stream);
    {
        long long total = (long long)ED * HDIM;
        int blocks = (int)((total + 255) / 256);
        scatter_add_edges<<<blocks, 256, 0, stream>>>(dt3, dt2, d_src, d_dst, total, 8);
    }
    gemm_bias_act<HDIM><<<(ND + 15) / 16, 256, 0, stream>>>(dt2, dW3, db3, dt4, ND, 1);
    gemm_bias_act<HDIM><<<(ND + 15) / 16, 256, 0, stream>>>(dt4, dW4, db4, dt3, ND, 0);
    colsum256<<<(ND + 255) / 256, 256, 0, stream>>>(dt3, pooled + 256, ND);

    // ---------------- head ----------------
    mlp_head<<<1, 256, 0, stream>>>(pooled, lW1, lb1, lW2, lb2, lW3, lb3, (float*)d_out);
}

// Round 2
// 1006.157 us; speedup vs baseline: 1.4304x; 1.4304x over previous
//
#include <hip/hip_runtime.h>
#include <hip/hip_bf16.h>

// ---------------------------------------------------------------------------
// BasicCountNet round 2:
//   - CSR-gather aggregation (no float atomics): build CSR per graph (deg
//     histogram -> 1-block scan -> fill), then node-parallel gather computing
//     self + neighbor-sum directly.
//   - fp32 GEMM restructured: 64 rows x 256 cols per block, thread = 16 rows
//     x 4 cols, ds_read_b128 A fragments, float4 W loads (FMA-bound).
// ---------------------------------------------------------------------------

#define NQ 64
#define EQ 512
#define ND 50000
#define ED 600000
#define FDIM 128
#define HDIM 256

// ---------------- CSR build ----------------

__global__ void count_deg(const int* __restrict__ dst, int* __restrict__ deg, int ne) {
    int e = blockIdx.x * 256 + threadIdx.x;
    if (e < ne) atomicAdd(&deg[dst[e]], 1);
}

// single block, 1024 threads: exclusive scan of deg[0..n) -> rowptr[0..n], cursor copy
__global__ void exclusive_scan_int(const int* __restrict__ deg, int* __restrict__ rowptr,
                                   int* __restrict__ cursor, int n) {
    __shared__ int part[1024];
    const int t = threadIdx.x;
    const int chunk = (n + 1023) / 1024;
    const int base = t * chunk;
    int s = 0;
    for (int i = 0; i < chunk; ++i) {
        int idx = base + i;
        if (idx < n) s += deg[idx];
    }
    part[t] = s;
    __syncthreads();
    for (int off = 1; off < 1024; off <<= 1) {
        int v = 0;
        if (t >= off) v = part[t - off];
        __syncthreads();
        if (t >= off) part[t] += v;
        __syncthreads();
    }
    if (t == 1023) rowptr[n] = part[1023];
    int run = (t == 0) ? 0 : part[t - 1];
    for (int i = 0; i < chunk; ++i) {
        int idx = base + i;
        if (idx < n) {
            rowptr[idx] = run;
            cursor[idx] = run;
            run += deg[idx];
        }
    }
}

__global__ void fill_csr(const int* __restrict__ src, const int* __restrict__ dst,
                         int* __restrict__ cursor, int* __restrict__ csrsrc, int ne) {
    int e = blockIdx.x * 256 + threadIdx.x;
    if (e < ne) {
        int p = atomicAdd(&cursor[dst[e]], 1);
        csrsrc[p] = src[e];
    }
}

// ---------------- aggregation: out[n] = x[n] + sum_{j in N(n)} x[j] ----------------
// one wave per node, F/64 floats per lane

template <int F>
__global__ void gin_aggregate(const float* __restrict__ x,
                              const int* __restrict__ rowptr,
                              const int* __restrict__ csrsrc,
                              float* __restrict__ out) {
    constexpr int VEC = F / 64;  // 4 (F=256) or 2 (F=128)
    const int node = blockIdx.x;
    const int t = threadIdx.x;  // 0..63
    const int beg = rowptr[node];
    const int end = rowptr[node + 1];

    float acc[VEC];
    {
        const float* p = x + (size_t)node * F + t * VEC;
        if constexpr (VEC == 4) {
            float4 v = *(const float4*)p;
            acc[0] = v.x; acc[1] = v.y; acc[2] = v.z; acc[3] = v.w;
        } else {
            float2 v = *(const float2*)p;
            acc[0] = v.x; acc[1] = v.y;
        }
    }
    int j = beg;
    for (; j + 1 < end; j += 2) {
        const int s0 = csrsrc[j];
        const int s1 = csrsrc[j + 1];
        const float* p0 = x + (size_t)s0 * F + t * VEC;
        const float* p1 = x + (size_t)s1 * F + t * VEC;
        if constexpr (VEC == 4) {
            float4 v0 = *(const float4*)p0;
            float4 v1 = *(const float4*)p1;
            acc[0] += v0.x + v1.x; acc[1] += v0.y + v1.y;
            acc[2] += v0.z + v1.z; acc[3] += v0.w + v1.w;
        } else {
            float2 v0 = *(const float2*)p0;
            float2 v1 = *(const float2*)p1;
            acc[0] += v0.x + v1.x; acc[1] += v0.y + v1.y;
        }
    }
    if (j < end) {
        const int s0 = csrsrc[j];
        const float* p0 = x + (size_t)s0 * F + t * VEC;
        if constexpr (VEC == 4) {
            float4 v0 = *(const float4*)p0;
            acc[0] += v0.x; acc[1] += v0.y; acc[2] += v0.z; acc[3] += v0.w;
        } else {
            float2 v0 = *(const float2*)p0;
            acc[0] += v0.x; acc[1] += v0.y;
        }
    }
    float* po = out + (size_t)node * F + t * VEC;
    if constexpr (VEC == 4) {
        float4 r; r.x = acc[0]; r.y = acc[1]; r.z = acc[2]; r.w = acc[3];
        *(float4*)po = r;
    } else {
        float2 r; r.x = acc[0]; r.y = acc[1];
        *(float2*)po = r;
    }
}

// ---------------- GEMM: C[N,256] = act(A[N,K] @ W[K,256] + b) ----------------
// block: 64 rows x 256 cols, 256 threads; thread = 16 rows x 4 cols

template <int K>
__global__ __launch_bounds__(256) void gemm64(const float* __restrict__ A,
                                              const float* __restrict__ W,
                                              const float* __restrict__ b,
                                              float* __restrict__ C,
                                              int N, int relu) {
    __shared__ __align__(16) float As[64 * K];
    const int row0 = blockIdx.x * 64;
    const int nrows = (N - row0 < 64) ? (N - row0) : 64;
    {
        const float4* srcv = (const float4*)(A + (size_t)row0 * K);
        float4* dstv = (float4*)As;
        const int n4 = nrows * K / 4;
        for (int i = threadIdx.x; i < n4; i += 256) dstv[i] = srcv[i];
    }
    __syncthreads();

    const int cg = threadIdx.x & 63;  // cols 4cg..4cg+3
    const int rg = threadIdx.x >> 6;  // rows 16rg..16rg+15

    float acc[16][4];
#pragma unroll
    for (int r = 0; r < 16; ++r)
#pragma unroll
        for (int c = 0; c < 4; ++c) acc[r][c] = 0.f;

    const float* Wc = W + 4 * cg;
    const float* Arow = As + rg * 16 * K;

    for (int k = 0; k < K; k += 4) {
        const float4 w0 = *(const float4*)(Wc + (size_t)(k + 0) * 256);
        const float4 w1 = *(const float4*)(Wc + (size_t)(k + 1) * 256);
        const float4 w2 = *(const float4*)(Wc + (size_t)(k + 2) * 256);
        const float4 w3 = *(const float4*)(Wc + (size_t)(k + 3) * 256);
#pragma unroll
        for (int r = 0; r < 16; ++r) {
            const float4 a = *(const float4*)(Arow + r * K + k);
            acc[r][0] += a.x * w0.x + a.y * w1.x + a.z * w2.x + a.w * w3.x;
            acc[r][1] += a.x * w0.y + a.y * w1.y + a.z * w2.y + a.w * w3.y;
            acc[r][2] += a.x * w0.z + a.y * w1.z + a.z * w2.z + a.w * w3.z;
            acc[r][3] += a.x * w0.w + a.y * w1.w + a.z * w2.w + a.w * w3.w;
        }
    }

    const float4 bv = *(const float4*)(b + 4 * cg);
#pragma unroll
    for (int r = 0; r < 16; ++r) {
        const int row = row0 + rg * 16 + r;
        if (row < N) {
            float4 v;
            v.x = acc[r][0] + bv.x;
            v.y = acc[r][1] + bv.y;
            v.z = acc[r][2] + bv.z;
            v.w = acc[r][3] + bv.w;
            if (relu) {
                v.x = fmaxf(v.x, 0.f); v.y = fmaxf(v.y, 0.f);
                v.z = fmaxf(v.z, 0.f); v.w = fmaxf(v.w, 0.f);
            }
            *(float4*)(C + (size_t)row * 256 + 4 * cg) = v;
        }
    }
}

// ---------------- pooling + head ----------------

__global__ void colsum256(const float* __restrict__ X, float* __restrict__ out, int N) {
    const int t = threadIdx.x;
    const int r0 = blockIdx.x * 256;
    const int rend = (r0 + 256 < N) ? (r0 + 256) : N;
    float acc = 0.f;
    for (int r = r0; r < rend; ++r) acc += X[(size_t)r * 256 + t];
    atomicAdd(&out[t], acc);
}

__global__ void mlp_head(const float* __restrict__ pooled,
                         const float* __restrict__ lW1, const float* __restrict__ lb1,
                         const float* __restrict__ lW2, const float* __restrict__ lb2,
                         const float* __restrict__ lW3, const float* __restrict__ lb3,
                         float* __restrict__ out) {
    __shared__ float h0[512];
    __shared__ float h1[256];
    __shared__ float h2[128];
    const int t = threadIdx.x;  // 256 threads
    h0[t] = pooled[t];
    h0[t + 256] = pooled[t + 256];
    __syncthreads();

    float acc = lb1[t];
    for (int k = 0; k < 512; ++k) acc += h0[k] * lW1[k * 256 + t];
    h1[t] = fmaxf(acc, 0.f);
    __syncthreads();

    if (t < 128) {
        float a = lb2[t];
        for (int k = 0; k < 256; ++k) a += h1[k] * lW2[k * 128 + t];
        h2[t] = fmaxf(a, 0.f);
    }
    __syncthreads();

    if (t < 8) {
        float a = lb3[t];
        for (int k = 0; k < 128; ++k) a += h2[k] * lW3[k * 8 + t];
        out[t] = fmaxf(a, 0.f);
    }
}

// ---------------------------------------------------------------------------

extern "C" void kernel_launch(void* const* d_in, const int* in_sizes, int n_in,
                              void* d_out, int out_size, void* d_ws, size_t ws_size,
                              hipStream_t stream) {
    const float* q_x  = (const float*)d_in[0];
    const float* d_x  = (const float*)d_in[1];
    const int*   q_el = (const int*)d_in[2];
    const int*   d_el = (const int*)d_in[3];
    const float* qW1 = (const float*)d_in[4];  const float* qb1 = (const float*)d_in[5];
    const float* qW2 = (const float*)d_in[6];  const float* qb2 = (const float*)d_in[7];
    const float* qW3 = (const float*)d_in[8];  const float* qb3 = (const float*)d_in[9];
    const float* qW4 = (const float*)d_in[10]; const float* qb4 = (const float*)d_in[11];
    const float* dW1 = (const float*)d_in[12]; const float* db1 = (const float*)d_in[13];
    const float* dW2 = (const float*)d_in[14]; const float* db2 = (const float*)d_in[15];
    const float* dW3 = (const float*)d_in[16]; const float* db3 = (const float*)d_in[17];
    const float* dW4 = (const float*)d_in[18]; const float* db4 = (const float*)d_in[19];
    const float* lW1 = (const float*)d_in[20]; const float* lb1 = (const float*)d_in[21];
    const float* lW2 = (const float*)d_in[22]; const float* lb2 = (const float*)d_in[23];
    const float* lW3 = (const float*)d_in[24]; const float* lb3 = (const float*)d_in[25];
    (void)in_sizes; (void)n_in; (void)out_size; (void)ws_size;

    const int* q_src = q_el;  const int* q_dst = q_el + EQ;
    const int* d_src = d_el;  const int* d_dst = d_el + ED;

    // ---- workspace layout ----
    char* wsb = (char*)d_ws;
    size_t off = 0;
    auto alloc = [&](size_t bytes) { void* p = wsb + off; off += (bytes + 255) & ~(size_t)255; return p; };

    float* da = (float*)alloc((size_t)ND * FDIM * 4);   // agg conv1 input (data)
    float* h1 = (float*)alloc((size_t)ND * HDIM * 4);
    float* h2 = (float*)alloc((size_t)ND * HDIM * 4);
    float* h3 = (float*)alloc((size_t)ND * HDIM * 4);
    float* qa = (float*)alloc((size_t)NQ * FDIM * 4);
    float* k1 = (float*)alloc((size_t)NQ * HDIM * 4);
    float* k2 = (float*)alloc((size_t)NQ * HDIM * 4);
    float* k3 = (float*)alloc((size_t)NQ * HDIM * 4);
    float* pooled = (float*)alloc(512 * 4);
    int* d_deg    = (int*)alloc((size_t)ND * 4);
    int* d_rowptr = (int*)alloc((size_t)(ND + 1) * 4);
    int* d_cursor = (int*)alloc((size_t)ND * 4);
    int* d_csrsrc = (int*)alloc((size_t)ED * 4);
    int* q_deg    = (int*)alloc((size_t)NQ * 4);
    int* q_rowptr = (int*)alloc((size_t)(NQ + 1) * 4);
    int* q_cursor = (int*)alloc((size_t)NQ * 4);
    int* q_csrsrc = (int*)alloc((size_t)EQ * 4);

    hipMemsetAsync(pooled, 0, 512 * 4, stream);
    hipMemsetAsync(d_deg, 0, (size_t)ND * 4, stream);
    hipMemsetAsync(q_deg, 0, (size_t)NQ * 4, stream);

    // ---- CSR build (both graphs) ----
    count_deg<<<(ED + 255) / 256, 256, 0, stream>>>(d_dst, d_deg, ED);
    count_deg<<<(EQ + 255) / 256, 256, 0, stream>>>(q_dst, q_deg, EQ);
    exclusive_scan_int<<<1, 1024, 0, stream>>>(d_deg, d_rowptr, d_cursor, ND);
    exclusive_scan_int<<<1, 1024, 0, stream>>>(q_deg, q_rowptr, q_cursor, NQ);
    fill_csr<<<(ED + 255) / 256, 256, 0, stream>>>(d_src, d_dst, d_cursor, d_csrsrc, ED);
    fill_csr<<<(EQ + 255) / 256, 256, 0, stream>>>(q_src, q_dst, q_cursor, q_csrsrc, EQ);

    // ---- query graph ----
    gin_aggregate<FDIM><<<NQ, 64, 0, stream>>>(q_x, q_rowptr, q_csrsrc, qa);
    gemm64<FDIM><<<(NQ + 63) / 64, 256, 0, stream>>>(qa, qW1, qb1, k1, NQ, 1);
    gemm64<HDIM><<<(NQ + 63) / 64, 256, 0, stream>>>(k1, qW2, qb2, k2, NQ, 1);  // inter-conv ReLU fused
    gin_aggregate<HDIM><<<NQ, 64, 0, stream>>>(k2, q_rowptr, q_csrsrc, k3);
    gemm64<HDIM><<<(NQ + 63) / 64, 256, 0, stream>>>(k3, qW3, qb3, k1, NQ, 1);
    gemm64<HDIM><<<(NQ + 63) / 64, 256, 0, stream>>>(k1, qW4, qb4, k3, NQ, 0);
    colsum256<<<(NQ + 255) / 256, 256, 0, stream>>>(k3, pooled, NQ);

    // ---- data graph ----
    gin_aggregate<FDIM><<<ND, 64, 0, stream>>>(d_x, d_rowptr, d_csrsrc, da);
    gemm64<FDIM><<<(ND + 63) / 64, 256, 0, stream>>>(da, dW1, db1, h1, ND, 1);
    gemm64<HDIM><<<(ND + 63) / 64, 256, 0, stream>>>(h1, dW2, db2, h2, ND, 1);  // inter-conv ReLU fused
    gin_aggregate<HDIM><<<ND, 64, 0, stream>>>(h2, d_rowptr, d_csrsrc, h3);
    gemm64<HDIM><<<(ND + 63) / 64, 256, 0, stream>>>(h3, dW3, db3, h1, ND, 1);
    gemm64<HDIM><<<(ND + 63) / 64, 256, 0, stream>>>(h1, dW4, db4, h3, ND, 0);
    colsum256<<<(ND + 255) / 256, 256, 0, stream>>>(h3, pooled + 256, ND);

    // ---- head ----
    mlp_head<<<1, 256, 0, stream>>>(pooled, lW1, lb1, lW2, lb2, lW3, lb3, (float*)d_out);
}

// Round 3
// 649.605 us; speedup vs baseline: 2.2154x; 1.5489x over previous
//
#include <hip/hip_runtime.h>
#include <hip/hip_bf16.h>

// ---------------------------------------------------------------------------
// BasicCountNet round 3:
//   - GEMMs moved to bf16 MFMA (mfma_f32_16x16x32_bf16), fp32 accumulate.
//     Weights packed once per launch into B-fragment order (coalesced 16B/lane
//     loads). A staged fp32->bf16 in LDS with XOR swizzle (bank-balanced
//     ds_read_b128). Block = 64 rows x 256 cols, 4 waves, 4x4 frags/wave.
//   - CSR-gather aggregation unchanged (round-2 win).
// ---------------------------------------------------------------------------

#define NQ 64
#define EQ 512
#define ND 50000
#define ED 600000
#define FDIM 128
#define HDIM 256

typedef __attribute__((ext_vector_type(8))) short short8;
typedef __attribute__((ext_vector_type(4))) float f32x4;

__device__ __forceinline__ unsigned short f2bf(float f) {
    union { float f; unsigned u; } v; v.f = f;
    unsigned r = v.u + 0x7FFF + ((v.u >> 16) & 1);   // RNE
    return (unsigned short)(r >> 16);
}

// ---------------- CSR build ----------------

__global__ void count_deg(const int* __restrict__ dst, int* __restrict__ deg, int ne) {
    int e = blockIdx.x * 256 + threadIdx.x;
    if (e < ne) atomicAdd(&deg[dst[e]], 1);
}

__global__ void exclusive_scan_int(const int* __restrict__ deg, int* __restrict__ rowptr,
                                   int* __restrict__ cursor, int n) {
    __shared__ int part[1024];
    const int t = threadIdx.x;
    const int chunk = (n + 1023) / 1024;
    const int base = t * chunk;
    int s = 0;
    for (int i = 0; i < chunk; ++i) {
        int idx = base + i;
        if (idx < n) s += deg[idx];
    }
    part[t] = s;
    __syncthreads();
    for (int off = 1; off < 1024; off <<= 1) {
        int v = 0;
        if (t >= off) v = part[t - off];
        __syncthreads();
        if (t >= off) part[t] += v;
        __syncthreads();
    }
    if (t == 1023) rowptr[n] = part[1023];
    int run = (t == 0) ? 0 : part[t - 1];
    for (int i = 0; i < chunk; ++i) {
        int idx = base + i;
        if (idx < n) {
            rowptr[idx] = run;
            cursor[idx] = run;
            run += deg[idx];
        }
    }
}

__global__ void fill_csr(const int* __restrict__ src, const int* __restrict__ dst,
                         int* __restrict__ cursor, int* __restrict__ csrsrc, int ne) {
    int e = blockIdx.x * 256 + threadIdx.x;
    if (e < ne) {
        int p = atomicAdd(&cursor[dst[e]], 1);
        csrsrc[p] = src[e];
    }
}

// ---------------- aggregation: out[n] = x[n] + sum_{j in N(n)} x[j] ----------------

template <int F>
__global__ void gin_aggregate(const float* __restrict__ x,
                              const int* __restrict__ rowptr,
                              const int* __restrict__ csrsrc,
                              float* __restrict__ out) {
    constexpr int VEC = F / 64;  // 4 (F=256) or 2 (F=128)
    const int node = blockIdx.x;
    const int t = threadIdx.x;  // 0..63
    const int beg = rowptr[node];
    const int end = rowptr[node + 1];

    float acc[VEC];
    {
        const float* p = x + (size_t)node * F + t * VEC;
        if constexpr (VEC == 4) {
            float4 v = *(const float4*)p;
            acc[0] = v.x; acc[1] = v.y; acc[2] = v.z; acc[3] = v.w;
        } else {
            float2 v = *(const float2*)p;
            acc[0] = v.x; acc[1] = v.y;
        }
    }
    int j = beg;
    for (; j + 1 < end; j += 2) {
        const int s0 = csrsrc[j];
        const int s1 = csrsrc[j + 1];
        const float* p0 = x + (size_t)s0 * F + t * VEC;
        const float* p1 = x + (size_t)s1 * F + t * VEC;
        if constexpr (VEC == 4) {
            float4 v0 = *(const float4*)p0;
            float4 v1 = *(const float4*)p1;
            acc[0] += v0.x + v1.x; acc[1] += v0.y + v1.y;
            acc[2] += v0.z + v1.z; acc[3] += v0.w + v1.w;
        } else {
            float2 v0 = *(const float2*)p0;
            float2 v1 = *(const float2*)p1;
            acc[0] += v0.x + v1.x; acc[1] += v0.y + v1.y;
        }
    }
    if (j < end) {
        const int s0 = csrsrc[j];
        const float* p0 = x + (size_t)s0 * F + t * VEC;
        if constexpr (VEC == 4) {
            float4 v0 = *(const float4*)p0;
            acc[0] += v0.x; acc[1] += v0.y; acc[2] += v0.z; acc[3] += v0.w;
        } else {
            float2 v0 = *(const float2*)p0;
            acc[0] += v0.x; acc[1] += v0.y;
        }
    }
    float* po = out + (size_t)node * F + t * VEC;
    if constexpr (VEC == 4) {
        float4 r; r.x = acc[0]; r.y = acc[1]; r.z = acc[2]; r.w = acc[3];
        *(float4*)po = r;
    } else {
        float2 r; r.x = acc[0]; r.y = acc[1];
        *(float2*)po = r;
    }
}

// ---------------- weight packing: W[K][256] fp32 -> bf16 B-fragments ----------------
// Wp layout: [ct(16)][kt(K/32)][lane(64)][j(8)] ; element = W[kt*32+(l>>4)*8+j][ct*16+(l&15)]

__global__ void pack_w(const float* __restrict__ W, unsigned short* __restrict__ Wp, int KT) {
    const int kt = blockIdx.x % KT;
    const int ct = blockIdx.x / KT;
    const int l = threadIdx.x;  // 0..63
    const int row = kt * 32 + (l >> 4) * 8;
    const int col = ct * 16 + (l & 15);
    short8 v;
#pragma unroll
    for (int j = 0; j < 8; ++j) v[j] = (short)f2bf(W[(size_t)(row + j) * 256 + col]);
    *(short8*)(Wp + (((size_t)(ct * KT + kt)) * 64 + l) * 8) = v;
}

// ---------------- GEMM: C[N,256] = act(A[N,K] @ W[K,256] + b) ----------------
// block: 64 rows x 256 cols, 4 waves; wave w owns cols w*64..w*64+63 (4x4 frags)

template <int K>
__global__ __launch_bounds__(256) void gemm_mfma(const float* __restrict__ A,
                                                 const unsigned short* __restrict__ Wp,
                                                 const float* __restrict__ bias,
                                                 float* __restrict__ C,
                                                 int N, int relu) {
    constexpr int KT = K / 32;
    __shared__ __align__(16) unsigned short As[64 * K];  // bf16, XOR-swizzled
    const int row0 = blockIdx.x * 64;
    const int tid = threadIdx.x;
    const int nrows = (N - row0 < 64) ? (N - row0) : 64;

    // stage A: fp32 -> bf16, swizzled 16B writes
    for (int idx = tid; idx < nrows * (K / 8); idx += 256) {
        const int r = idx / (K / 8);
        const int k8 = (idx % (K / 8)) * 8;
        const float* p = A + (size_t)(row0 + r) * K + k8;
        const float4 v0 = *(const float4*)p;
        const float4 v1 = *(const float4*)(p + 4);
        short8 v;
        v[0] = (short)f2bf(v0.x); v[1] = (short)f2bf(v0.y);
        v[2] = (short)f2bf(v0.z); v[3] = (short)f2bf(v0.w);
        v[4] = (short)f2bf(v1.x); v[5] = (short)f2bf(v1.y);
        v[6] = (short)f2bf(v1.z); v[7] = (short)f2bf(v1.w);
        unsigned byte = (unsigned)(r * K + k8) * 2;
        byte ^= (unsigned)((r & 7) << 4);
        *(short8*)((char*)As + byte) = v;
    }
    __syncthreads();

    const int lane = tid & 63;
    const int wv = tid >> 6;        // wave id: cols wv*64..+63
    const int lrow = lane & 15;
    const int lk2 = (lane >> 4) * 8;  // k sub-offset within 32

    f32x4 acc[4][4];
#pragma unroll
    for (int fm = 0; fm < 4; ++fm)
#pragma unroll
        for (int fn = 0; fn < 4; ++fn) acc[fm][fn] = (f32x4)(0.f);

    const unsigned short* WpBase = Wp + ((size_t)(wv * 4) * KT * 64 + lane) * 8;

    for (int kt = 0; kt < KT; ++kt) {
        short8 a[4], bf[4];
#pragma unroll
        for (int fm = 0; fm < 4; ++fm) {
            const int r = fm * 16 + lrow;
            unsigned byte = (unsigned)(r * K + kt * 32 + lk2) * 2;
            byte ^= (unsigned)((r & 7) << 4);
            a[fm] = *(const short8*)((const char*)As + byte);
        }
#pragma unroll
        for (int fn = 0; fn < 4; ++fn)
            bf[fn] = *(const short8*)(WpBase + ((size_t)fn * KT + kt) * 64 * 8);
#pragma unroll
        for (int fm = 0; fm < 4; ++fm)
#pragma unroll
            for (int fn = 0; fn < 4; ++fn)
                acc[fm][fn] = __builtin_amdgcn_mfma_f32_16x16x32_bf16(
                    a[fm], bf[fn], acc[fm][fn], 0, 0, 0);
    }

    // epilogue: C/D mapping col=lane&15, row=(lane>>4)*4+reg  [m89]
#pragma unroll
    for (int fn = 0; fn < 4; ++fn) {
        const int col = wv * 64 + fn * 16 + lrow;
        const float bv = bias[col];
#pragma unroll
        for (int fm = 0; fm < 4; ++fm) {
            const int rbase = row0 + fm * 16 + (lane >> 4) * 4;
#pragma unroll
            for (int r = 0; r < 4; ++r) {
                const int row = rbase + r;
                if (row < N) {
                    float v = acc[fm][fn][r] + bv;
                    if (relu) v = fmaxf(v, 0.f);
                    C[(size_t)row * 256 + col] = v;
                }
            }
        }
    }
}

// ---------------- pooling + head ----------------

__global__ void colsum256(const float* __restrict__ X, float* __restrict__ out, int N) {
    const int t = threadIdx.x;
    const int r0 = blockIdx.x * 256;
    const int rend = (r0 + 256 < N) ? (r0 + 256) : N;
    float acc = 0.f;
    for (int r = r0; r < rend; ++r) acc += X[(size_t)r * 256 + t];
    atomicAdd(&out[t], acc);
}

__global__ void mlp_head(const float* __restrict__ pooled,
                         const float* __restrict__ lW1, const float* __restrict__ lb1,
                         const float* __restrict__ lW2, const float* __restrict__ lb2,
                         const float* __restrict__ lW3, const float* __restrict__ lb3,
                         float* __restrict__ out) {
    __shared__ float h0[512];
    __shared__ float h1[256];
    __shared__ float h2[128];
    const int t = threadIdx.x;  // 256 threads
    h0[t] = pooled[t];
    h0[t + 256] = pooled[t + 256];
    __syncthreads();

    float acc = lb1[t];
    for (int k = 0; k < 512; ++k) acc += h0[k] * lW1[k * 256 + t];
    h1[t] = fmaxf(acc, 0.f);
    __syncthreads();

    if (t < 128) {
        float a = lb2[t];
        for (int k = 0; k < 256; ++k) a += h1[k] * lW2[k * 128 + t];
        h2[t] = fmaxf(a, 0.f);
    }
    __syncthreads();

    if (t < 8) {
        float a = lb3[t];
        for (int k = 0; k < 128; ++k) a += h2[k] * lW3[k * 8 + t];
        out[t] = fmaxf(a, 0.f);
    }
}

// ---------------------------------------------------------------------------

extern "C" void kernel_launch(void* const* d_in, const int* in_sizes, int n_in,
                              void* d_out, int out_size, void* d_ws, size_t ws_size,
                              hipStream_t stream) {
    const float* q_x  = (const float*)d_in[0];
    const float* d_x  = (const float*)d_in[1];
    const int*   q_el = (const int*)d_in[2];
    const int*   d_el = (const int*)d_in[3];
    const float* qW1 = (const float*)d_in[4];  const float* qb1 = (const float*)d_in[5];
    const float* qW2 = (const float*)d_in[6];  const float* qb2 = (const float*)d_in[7];
    const float* qW3 = (const float*)d_in[8];  const float* qb3 = (const float*)d_in[9];
    const float* qW4 = (const float*)d_in[10]; const float* qb4 = (const float*)d_in[11];
    const float* dW1 = (const float*)d_in[12]; const float* db1 = (const float*)d_in[13];
    const float* dW2 = (const float*)d_in[14]; const float* db2 = (const float*)d_in[15];
    const float* dW3 = (const float*)d_in[16]; const float* db3 = (const float*)d_in[17];
    const float* dW4 = (const float*)d_in[18]; const float* db4 = (const float*)d_in[19];
    const float* lW1 = (const float*)d_in[20]; const float* lb1 = (const float*)d_in[21];
    const float* lW2 = (const float*)d_in[22]; const float* lb2 = (const float*)d_in[23];
    const float* lW3 = (const float*)d_in[24]; const float* lb3 = (const float*)d_in[25];
    (void)in_sizes; (void)n_in; (void)out_size; (void)ws_size;

    const int* q_src = q_el;  const int* q_dst = q_el + EQ;
    const int* d_src = d_el;  const int* d_dst = d_el + ED;

    // ---- workspace layout ----
    char* wsb = (char*)d_ws;
    size_t off = 0;
    auto alloc = [&](size_t bytes) { void* p = wsb + off; off += (bytes + 255) & ~(size_t)255; return p; };

    float* da = (float*)alloc((size_t)ND * FDIM * 4);
    float* h1 = (float*)alloc((size_t)ND * HDIM * 4);
    float* h2 = (float*)alloc((size_t)ND * HDIM * 4);
    float* h3 = (float*)alloc((size_t)ND * HDIM * 4);
    float* qa = (float*)alloc((size_t)NQ * FDIM * 4);
    float* k1 = (float*)alloc((size_t)NQ * HDIM * 4);
    float* k2 = (float*)alloc((size_t)NQ * HDIM * 4);
    float* k3 = (float*)alloc((size_t)NQ * HDIM * 4);
    float* pooled = (float*)alloc(512 * 4);
    int* d_deg    = (int*)alloc((size_t)ND * 4);
    int* d_rowptr = (int*)alloc((size_t)(ND + 1) * 4);
    int* d_cursor = (int*)alloc((size_t)ND * 4);
    int* d_csrsrc = (int*)alloc((size_t)ED * 4);
    int* q_deg    = (int*)alloc((size_t)NQ * 4);
    int* q_rowptr = (int*)alloc((size_t)(NQ + 1) * 4);
    int* q_cursor = (int*)alloc((size_t)NQ * 4);
    int* q_csrsrc = (int*)alloc((size_t)EQ * 4);
    // packed bf16 weights (B-fragment order)
    unsigned short* pdW1 = (unsigned short*)alloc((size_t)FDIM * 256 * 2);
    unsigned short* pdW2 = (unsigned short*)alloc((size_t)HDIM * 256 * 2);
    unsigned short* pdW3 = (unsigned short*)alloc((size_t)HDIM * 256 * 2);
    unsigned short* pdW4 = (unsigned short*)alloc((size_t)HDIM * 256 * 2);
    unsigned short* pqW1 = (unsigned short*)alloc((size_t)FDIM * 256 * 2);
    unsigned short* pqW2 = (unsigned short*)alloc((size_t)HDIM * 256 * 2);
    unsigned short* pqW3 = (unsigned short*)alloc((size_t)HDIM * 256 * 2);
    unsigned short* pqW4 = (unsigned short*)alloc((size_t)HDIM * 256 * 2);

    hipMemsetAsync(pooled, 0, 512 * 4, stream);
    hipMemsetAsync(d_deg, 0, (size_t)ND * 4, stream);
    hipMemsetAsync(q_deg, 0, (size_t)NQ * 4, stream);

    // ---- weight packing ----
    pack_w<<<16 * (FDIM / 32), 64, 0, stream>>>(dW1, pdW1, FDIM / 32);
    pack_w<<<16 * (HDIM / 32), 64, 0, stream>>>(dW2, pdW2, HDIM / 32);
    pack_w<<<16 * (HDIM / 32), 64, 0, stream>>>(dW3, pdW3, HDIM / 32);
    pack_w<<<16 * (HDIM / 32), 64, 0, stream>>>(dW4, pdW4, HDIM / 32);
    pack_w<<<16 * (FDIM / 32), 64, 0, stream>>>(qW1, pqW1, FDIM / 32);
    pack_w<<<16 * (HDIM / 32), 64, 0, stream>>>(qW2, pqW2, HDIM / 32);
    pack_w<<<16 * (HDIM / 32), 64, 0, stream>>>(qW3, pqW3, HDIM / 32);
    pack_w<<<16 * (HDIM / 32), 64, 0, stream>>>(qW4, pqW4, HDIM / 32);

    // ---- CSR build ----
    count_deg<<<(ED + 255) / 256, 256, 0, stream>>>(d_dst, d_deg, ED);
    count_deg<<<(EQ + 255) / 256, 256, 0, stream>>>(q_dst, q_deg, EQ);
    exclusive_scan_int<<<1, 1024, 0, stream>>>(d_deg, d_rowptr, d_cursor, ND);
    exclusive_scan_int<<<1, 1024, 0, stream>>>(q_deg, q_rowptr, q_cursor, NQ);
    fill_csr<<<(ED + 255) / 256, 256, 0, stream>>>(d_src, d_dst, d_cursor, d_csrsrc, ED);
    fill_csr<<<(EQ + 255) / 256, 256, 0, stream>>>(q_src, q_dst, q_cursor, q_csrsrc, EQ);

    // ---- query graph ----
    gin_aggregate<FDIM><<<NQ, 64, 0, stream>>>(q_x, q_rowptr, q_csrsrc, qa);
    gemm_mfma<FDIM><<<(NQ + 63) / 64, 256, 0, stream>>>(qa, pqW1, qb1, k1, NQ, 1);
    gemm_mfma<HDIM><<<(NQ + 63) / 64, 256, 0, stream>>>(k1, pqW2, qb2, k2, NQ, 1);
    gin_aggregate<HDIM><<<NQ, 64, 0, stream>>>(k2, q_rowptr, q_csrsrc, k3);
    gemm_mfma<HDIM><<<(NQ + 63) / 64, 256, 0, stream>>>(k3, pqW3, qb3, k1, NQ, 1);
    gemm_mfma<HDIM><<<(NQ + 63) / 64, 256, 0, stream>>>(k1, pqW4, qb4, k3, NQ, 0);
    colsum256<<<(NQ + 255) / 256, 256, 0, stream>>>(k3, pooled, NQ);

    // ---- data graph ----
    gin_aggregate<FDIM><<<ND, 64, 0, stream>>>(d_x, d_rowptr, d_csrsrc, da);
    gemm_mfma<FDIM><<<(ND + 63) / 64, 256, 0, stream>>>(da, pdW1, db1, h1, ND, 1);
    gemm_mfma<HDIM><<<(ND + 63) / 64, 256, 0, stream>>>(h1, pdW2, db2, h2, ND, 1);
    gin_aggregate<HDIM><<<ND, 64, 0, stream>>>(h2, d_rowptr, d_csrsrc, h3);
    gemm_mfma<HDIM><<<(ND + 63) / 64, 256, 0, stream>>>(h3, pdW3, db3, h1, ND, 1);
    gemm_mfma<HDIM><<<(ND + 63) / 64, 256, 0, stream>>>(h1, pdW4, db4, h3, ND, 0);
    colsum256<<<(ND + 255) / 256, 256, 0, stream>>>(h3, pooled + 256, ND);

    // ---- head ----
    mlp_head<<<1, 256, 0, stream>>>(pooled, lW1, lb1, lW2, lb2, lW3, lb3, (float*)d_out);
}

// Round 4
// 491.009 us; speedup vs baseline: 2.9310x; 1.3230x over previous
//
#include <hip/hip_runtime.h>
#include <hip/hip_bf16.h>

// ---------------------------------------------------------------------------
// BasicCountNet round 4:
//   - multi-block 3-phase exclusive scan (replaces 124us single-block scan)
//   - column-sum pooling fused into final GEMM epilogue (shfl_xor reduce +
//     one atomicAdd per column per block); colsum256 kernel removed
//   - bf16 MFMA GEMMs + CSR-gather aggregation unchanged (round-2/3 wins)
// ---------------------------------------------------------------------------

#define NQ 64
#define EQ 512
#define ND 50000
#define ED 600000
#define FDIM 128
#define HDIM 256

typedef __attribute__((ext_vector_type(8))) short short8;
typedef __attribute__((ext_vector_type(4))) float f32x4;

__device__ __forceinline__ unsigned short f2bf(float f) {
    union { float f; unsigned u; } v; v.f = f;
    unsigned r = v.u + 0x7FFF + ((v.u >> 16) & 1);   // RNE
    return (unsigned short)(r >> 16);
}

// ---------------- CSR build ----------------

__global__ void count_deg(const int* __restrict__ dst, int* __restrict__ deg, int ne) {
    int e = blockIdx.x * 256 + threadIdx.x;
    if (e < ne) atomicAdd(&deg[dst[e]], 1);
}

// phase1: per-block inclusive scan of 256 elems -> exclusive local prefix in rowptr,
//         block total in bsum
__global__ void scan_phase1(const int* __restrict__ deg, int* __restrict__ rowptr,
                            int* __restrict__ bsum, int n) {
    __shared__ int sh[256];
    const int t = threadIdx.x;
    const int i = blockIdx.x * 256 + t;
    const int v = (i < n) ? deg[i] : 0;
    sh[t] = v;
    __syncthreads();
    for (int off = 1; off < 256; off <<= 1) {
        int x = (t >= off) ? sh[t - off] : 0;
        __syncthreads();
        sh[t] += x;
        __syncthreads();
    }
    if (i < n) rowptr[i] = sh[t] - v;
    if (t == 255) bsum[blockIdx.x] = sh[255];
}

// phase2: single block scans <=256 block sums -> exclusive offsets; total -> rowptr[n]
__global__ void scan_phase2(const int* __restrict__ bsum, int* __restrict__ boff,
                            int* __restrict__ rowptr_n, int nb) {
    __shared__ int sh[256];
    const int t = threadIdx.x;
    const int v = (t < nb) ? bsum[t] : 0;
    sh[t] = v;
    __syncthreads();
    for (int off = 1; off < 256; off <<= 1) {
        int x = (t >= off) ? sh[t - off] : 0;
        __syncthreads();
        sh[t] += x;
        __syncthreads();
    }
    if (t < nb) boff[t] = sh[t] - v;
    if (t == 255) *rowptr_n = sh[255];
}

// phase3: rowptr[i] += boff[block]; cursor[i] = rowptr[i]
__global__ void scan_phase3(int* __restrict__ rowptr, const int* __restrict__ boff,
                            int* __restrict__ cursor, int n) {
    const int i = blockIdx.x * 256 + threadIdx.x;
    if (i < n) {
        const int r = rowptr[i] + boff[blockIdx.x];
        rowptr[i] = r;
        cursor[i] = r;
    }
}

__global__ void fill_csr(const int* __restrict__ src, const int* __restrict__ dst,
                         int* __restrict__ cursor, int* __restrict__ csrsrc, int ne) {
    int e = blockIdx.x * 256 + threadIdx.x;
    if (e < ne) {
        int p = atomicAdd(&cursor[dst[e]], 1);
        csrsrc[p] = src[e];
    }
}

// ---------------- aggregation: out[n] = x[n] + sum_{j in N(n)} x[j] ----------------

template <int F>
__global__ void gin_aggregate(const float* __restrict__ x,
                              const int* __restrict__ rowptr,
                              const int* __restrict__ csrsrc,
                              float* __restrict__ out) {
    constexpr int VEC = F / 64;  // 4 (F=256) or 2 (F=128)
    const int node = blockIdx.x;
    const int t = threadIdx.x;  // 0..63
    const int beg = rowptr[node];
    const int end = rowptr[node + 1];

    float acc[VEC];
    {
        const float* p = x + (size_t)node * F + t * VEC;
        if constexpr (VEC == 4) {
            float4 v = *(const float4*)p;
            acc[0] = v.x; acc[1] = v.y; acc[2] = v.z; acc[3] = v.w;
        } else {
            float2 v = *(const float2*)p;
            acc[0] = v.x; acc[1] = v.y;
        }
    }
    int j = beg;
    for (; j + 1 < end; j += 2) {
        const int s0 = csrsrc[j];
        const int s1 = csrsrc[j + 1];
        const float* p0 = x + (size_t)s0 * F + t * VEC;
        const float* p1 = x + (size_t)s1 * F + t * VEC;
        if constexpr (VEC == 4) {
            float4 v0 = *(const float4*)p0;
            float4 v1 = *(const float4*)p1;
            acc[0] += v0.x + v1.x; acc[1] += v0.y + v1.y;
            acc[2] += v0.z + v1.z; acc[3] += v0.w + v1.w;
        } else {
            float2 v0 = *(const float2*)p0;
            float2 v1 = *(const float2*)p1;
            acc[0] += v0.x + v1.x; acc[1] += v0.y + v1.y;
        }
    }
    if (j < end) {
        const int s0 = csrsrc[j];
        const float* p0 = x + (size_t)s0 * F + t * VEC;
        if constexpr (VEC == 4) {
            float4 v0 = *(const float4*)p0;
            acc[0] += v0.x; acc[1] += v0.y; acc[2] += v0.z; acc[3] += v0.w;
        } else {
            float2 v0 = *(const float2*)p0;
            acc[0] += v0.x; acc[1] += v0.y;
        }
    }
    float* po = out + (size_t)node * F + t * VEC;
    if constexpr (VEC == 4) {
        float4 r; r.x = acc[0]; r.y = acc[1]; r.z = acc[2]; r.w = acc[3];
        *(float4*)po = r;
    } else {
        float2 r; r.x = acc[0]; r.y = acc[1];
        *(float2*)po = r;
    }
}

// ---------------- weight packing: W[K][256] fp32 -> bf16 B-fragments ----------------
// Wp layout: [ct(16)][kt(K/32)][lane(64)][j(8)] ; element = W[kt*32+(l>>4)*8+j][ct*16+(l&15)]

__global__ void pack_w(const float* __restrict__ W, unsigned short* __restrict__ Wp, int KT) {
    const int kt = blockIdx.x % KT;
    const int ct = blockIdx.x / KT;
    const int l = threadIdx.x;  // 0..63
    const int row = kt * 32 + (l >> 4) * 8;
    const int col = ct * 16 + (l & 15);
    short8 v;
#pragma unroll
    for (int j = 0; j < 8; ++j) v[j] = (short)f2bf(W[(size_t)(row + j) * 256 + col]);
    *(short8*)(Wp + (((size_t)(ct * KT + kt)) * 64 + l) * 8) = v;
}

// ---------------- GEMM: C[N,256] = act(A[N,K] @ W[K,256] + b) ----------------
// block: 64 rows x 256 cols, 4 waves; wave w owns cols w*64..w*64+63 (4x4 frags)
// pool != nullptr: also atomicAdd per-block column sums of C into pool[col]

template <int K>
__global__ __launch_bounds__(256) void gemm_mfma(const float* __restrict__ A,
                                                 const unsigned short* __restrict__ Wp,
                                                 const float* __restrict__ bias,
                                                 float* __restrict__ C,
                                                 int N, int relu,
                                                 float* __restrict__ pool) {
    constexpr int KT = K / 32;
    __shared__ __align__(16) unsigned short As[64 * K];  // bf16, XOR-swizzled
    const int row0 = blockIdx.x * 64;
    const int tid = threadIdx.x;
    const int nrows = (N - row0 < 64) ? (N - row0) : 64;

    // stage A: fp32 -> bf16, swizzled 16B writes
    for (int idx = tid; idx < nrows * (K / 8); idx += 256) {
        const int r = idx / (K / 8);
        const int k8 = (idx % (K / 8)) * 8;
        const float* p = A + (size_t)(row0 + r) * K + k8;
        const float4 v0 = *(const float4*)p;
        const float4 v1 = *(const float4*)(p + 4);
        short8 v;
        v[0] = (short)f2bf(v0.x); v[1] = (short)f2bf(v0.y);
        v[2] = (short)f2bf(v0.z); v[3] = (short)f2bf(v0.w);
        v[4] = (short)f2bf(v1.x); v[5] = (short)f2bf(v1.y);
        v[6] = (short)f2bf(v1.z); v[7] = (short)f2bf(v1.w);
        unsigned byte = (unsigned)(r * K + k8) * 2;
        byte ^= (unsigned)((r & 7) << 4);
        *(short8*)((char*)As + byte) = v;
    }
    __syncthreads();

    const int lane = tid & 63;
    const int wv = tid >> 6;        // wave id: cols wv*64..+63
    const int lrow = lane & 15;
    const int lk2 = (lane >> 4) * 8;  // k sub-offset within 32

    f32x4 acc[4][4];
#pragma unroll
    for (int fm = 0; fm < 4; ++fm)
#pragma unroll
        for (int fn = 0; fn < 4; ++fn) acc[fm][fn] = (f32x4)(0.f);

    const unsigned short* WpBase = Wp + ((size_t)(wv * 4) * KT * 64 + lane) * 8;

    for (int kt = 0; kt < KT; ++kt) {
        short8 a[4], bf[4];
#pragma unroll
        for (int fm = 0; fm < 4; ++fm) {
            const int r = fm * 16 + lrow;
            unsigned byte = (unsigned)(r * K + kt * 32 + lk2) * 2;
            byte ^= (unsigned)((r & 7) << 4);
            a[fm] = *(const short8*)((const char*)As + byte);
        }
#pragma unroll
        for (int fn = 0; fn < 4; ++fn)
            bf[fn] = *(const short8*)(WpBase + ((size_t)fn * KT + kt) * 64 * 8);
#pragma unroll
        for (int fm = 0; fm < 4; ++fm)
#pragma unroll
            for (int fn = 0; fn < 4; ++fn)
                acc[fm][fn] = __builtin_amdgcn_mfma_f32_16x16x32_bf16(
                    a[fm], bf[fn], acc[fm][fn], 0, 0, 0);
    }

    // epilogue: C/D mapping col=lane&15, row=(lane>>4)*4+reg  [m89]
#pragma unroll
    for (int fn = 0; fn < 4; ++fn) {
        const int col = wv * 64 + fn * 16 + lrow;
        const float bv = bias[col];
        float ps = 0.f;  // partial colsum (rows this lane owns, row<N)
#pragma unroll
        for (int fm = 0; fm < 4; ++fm) {
            const int rbase = row0 + fm * 16 + (lane >> 4) * 4;
#pragma unroll
            for (int r = 0; r < 4; ++r) {
                const int row = rbase + r;
                if (row < N) {
                    float v = acc[fm][fn][r] + bv;
                    if (relu) v = fmaxf(v, 0.f);
                    C[(size_t)row * 256 + col] = v;
                    ps += v;
                }
            }
        }
        if (pool) {
            // combine the 4 row-groups (lanes lrow, lrow+16, lrow+32, lrow+48)
            ps += __shfl_xor(ps, 16);
            ps += __shfl_xor(ps, 32);
            if ((lane >> 4) == 0) atomicAdd(&pool[col], ps);
        }
    }
}

// ---------------- head ----------------

__global__ void mlp_head(const float* __restrict__ pooled,
                         const float* __restrict__ lW1, const float* __restrict__ lb1,
                         const float* __restrict__ lW2, const float* __restrict__ lb2,
                         const float* __restrict__ lW3, const float* __restrict__ lb3,
                         float* __restrict__ out) {
    __shared__ float h0[512];
    __shared__ float h1[256];
    __shared__ float h2[128];
    const int t = threadIdx.x;  // 256 threads
    h0[t] = pooled[t];
    h0[t + 256] = pooled[t + 256];
    __syncthreads();

    float acc = lb1[t];
    for (int k = 0; k < 512; ++k) acc += h0[k] * lW1[k * 256 + t];
    h1[t] = fmaxf(acc, 0.f);
    __syncthreads();

    if (t < 128) {
        float a = lb2[t];
        for (int k = 0; k < 256; ++k) a += h1[k] * lW2[k * 128 + t];
        h2[t] = fmaxf(a, 0.f);
    }
    __syncthreads();

    if (t < 8) {
        float a = lb3[t];
        for (int k = 0; k < 128; ++k) a += h2[k] * lW3[k * 8 + t];
        out[t] = fmaxf(a, 0.f);
    }
}

// ---------------------------------------------------------------------------

extern "C" void kernel_launch(void* const* d_in, const int* in_sizes, int n_in,
                              void* d_out, int out_size, void* d_ws, size_t ws_size,
                              hipStream_t stream) {
    const float* q_x  = (const float*)d_in[0];
    const float* d_x  = (const float*)d_in[1];
    const int*   q_el = (const int*)d_in[2];
    const int*   d_el = (const int*)d_in[3];
    const float* qW1 = (const float*)d_in[4];  const float* qb1 = (const float*)d_in[5];
    const float* qW2 = (const float*)d_in[6];  const float* qb2 = (const float*)d_in[7];
    const float* qW3 = (const float*)d_in[8];  const float* qb3 = (const float*)d_in[9];
    const float* qW4 = (const float*)d_in[10]; const float* qb4 = (const float*)d_in[11];
    const float* dW1 = (const float*)d_in[12]; const float* db1 = (const float*)d_in[13];
    const float* dW2 = (const float*)d_in[14]; const float* db2 = (const float*)d_in[15];
    const float* dW3 = (const float*)d_in[16]; const float* db3 = (const float*)d_in[17];
    const float* dW4 = (const float*)d_in[18]; const float* db4 = (const float*)d_in[19];
    const float* lW1 = (const float*)d_in[20]; const float* lb1 = (const float*)d_in[21];
    const float* lW2 = (const float*)d_in[22]; const float* lb2 = (const float*)d_in[23];
    const float* lW3 = (const float*)d_in[24]; const float* lb3 = (const float*)d_in[25];
    (void)in_sizes; (void)n_in; (void)out_size; (void)ws_size;

    const int* q_src = q_el;  const int* q_dst = q_el + EQ;
    const int* d_src = d_el;  const int* d_dst = d_el + ED;

    // ---- workspace layout ----
    char* wsb = (char*)d_ws;
    size_t off = 0;
    auto alloc = [&](size_t bytes) { void* p = wsb + off; off += (bytes + 255) & ~(size_t)255; return p; };

    float* da = (float*)alloc((size_t)ND * FDIM * 4);
    float* h1 = (float*)alloc((size_t)ND * HDIM * 4);
    float* h2 = (float*)alloc((size_t)ND * HDIM * 4);
    float* h3 = (float*)alloc((size_t)ND * HDIM * 4);
    float* qa = (float*)alloc((size_t)NQ * FDIM * 4);
    float* k1 = (float*)alloc((size_t)NQ * HDIM * 4);
    float* k2 = (float*)alloc((size_t)NQ * HDIM * 4);
    float* k3 = (float*)alloc((size_t)NQ * HDIM * 4);
    float* pooled = (float*)alloc(512 * 4);
    int* d_deg    = (int*)alloc((size_t)ND * 4);
    int* d_rowptr = (int*)alloc((size_t)(ND + 1) * 4);
    int* d_cursor = (int*)alloc((size_t)ND * 4);
    int* d_csrsrc = (int*)alloc((size_t)ED * 4);
    int* d_bsum   = (int*)alloc(256 * 4);
    int* d_boff   = (int*)alloc(256 * 4);
    int* q_deg    = (int*)alloc((size_t)NQ * 4);
    int* q_rowptr = (int*)alloc((size_t)(NQ + 1) * 4);
    int* q_cursor = (int*)alloc((size_t)NQ * 4);
    int* q_csrsrc = (int*)alloc((size_t)EQ * 4);
    int* q_bsum   = (int*)alloc(256 * 4);
    int* q_boff   = (int*)alloc(256 * 4);
    // packed bf16 weights (B-fragment order)
    unsigned short* pdW1 = (unsigned short*)alloc((size_t)FDIM * 256 * 2);
    unsigned short* pdW2 = (unsigned short*)alloc((size_t)HDIM * 256 * 2);
    unsigned short* pdW3 = (unsigned short*)alloc((size_t)HDIM * 256 * 2);
    unsigned short* pdW4 = (unsigned short*)alloc((size_t)HDIM * 256 * 2);
    unsigned short* pqW1 = (unsigned short*)alloc((size_t)FDIM * 256 * 2);
    unsigned short* pqW2 = (unsigned short*)alloc((size_t)HDIM * 256 * 2);
    unsigned short* pqW3 = (unsigned short*)alloc((size_t)HDIM * 256 * 2);
    unsigned short* pqW4 = (unsigned short*)alloc((size_t)HDIM * 256 * 2);

    hipMemsetAsync(pooled, 0, 512 * 4, stream);
    hipMemsetAsync(d_deg, 0, (size_t)ND * 4, stream);
    hipMemsetAsync(q_deg, 0, (size_t)NQ * 4, stream);

    // ---- weight packing ----
    pack_w<<<16 * (FDIM / 32), 64, 0, stream>>>(dW1, pdW1, FDIM / 32);
    pack_w<<<16 * (HDIM / 32), 64, 0, stream>>>(dW2, pdW2, HDIM / 32);
    pack_w<<<16 * (HDIM / 32), 64, 0, stream>>>(dW3, pdW3, HDIM / 32);
    pack_w<<<16 * (HDIM / 32), 64, 0, stream>>>(dW4, pdW4, HDIM / 32);
    pack_w<<<16 * (FDIM / 32), 64, 0, stream>>>(qW1, pqW1, FDIM / 32);
    pack_w<<<16 * (HDIM / 32), 64, 0, stream>>>(qW2, pqW2, HDIM / 32);
    pack_w<<<16 * (HDIM / 32), 64, 0, stream>>>(qW3, pqW3, HDIM / 32);
    pack_w<<<16 * (HDIM / 32), 64, 0, stream>>>(qW4, pqW4, HDIM / 32);

    // ---- CSR build ----
    const int d_nb = (ND + 255) / 256;   // 196
    const int q_nb = (NQ + 255) / 256;   // 1
    count_deg<<<(ED + 255) / 256, 256, 0, stream>>>(d_dst, d_deg, ED);
    count_deg<<<(EQ + 255) / 256, 256, 0, stream>>>(q_dst, q_deg, EQ);
    scan_phase1<<<d_nb, 256, 0, stream>>>(d_deg, d_rowptr, d_bsum, ND);
    scan_phase1<<<q_nb, 256, 0, stream>>>(q_deg, q_rowptr, q_bsum, NQ);
    scan_phase2<<<1, 256, 0, stream>>>(d_bsum, d_boff, d_rowptr + ND, d_nb);
    scan_phase2<<<1, 256, 0, stream>>>(q_bsum, q_boff, q_rowptr + NQ, q_nb);
    scan_phase3<<<d_nb, 256, 0, stream>>>(d_rowptr, d_boff, d_cursor, ND);
    scan_phase3<<<q_nb, 256, 0, stream>>>(q_rowptr, q_boff, q_cursor, NQ);
    fill_csr<<<(ED + 255) / 256, 256, 0, stream>>>(d_src, d_dst, d_cursor, d_csrsrc, ED);
    fill_csr<<<(EQ + 255) / 256, 256, 0, stream>>>(q_src, q_dst, q_cursor, q_csrsrc, EQ);

    // ---- query graph ----
    gin_aggregate<FDIM><<<NQ, 64, 0, stream>>>(q_x, q_rowptr, q_csrsrc, qa);
    gemm_mfma<FDIM><<<(NQ + 63) / 64, 256, 0, stream>>>(qa, pqW1, qb1, k1, NQ, 1, nullptr);
    gemm_mfma<HDIM><<<(NQ + 63) / 64, 256, 0, stream>>>(k1, pqW2, qb2, k2, NQ, 1, nullptr);
    gin_aggregate<HDIM><<<NQ, 64, 0, stream>>>(k2, q_rowptr, q_csrsrc, k3);
    gemm_mfma<HDIM><<<(NQ + 63) / 64, 256, 0, stream>>>(k3, pqW3, qb3, k1, NQ, 1, nullptr);
    gemm_mfma<HDIM><<<(NQ + 63) / 64, 256, 0, stream>>>(k1, pqW4, qb4, k3, NQ, 0, pooled);

    // ---- data graph ----
    gin_aggregate<FDIM><<<ND, 64, 0, stream>>>(d_x, d_rowptr, d_csrsrc, da);
    gemm_mfma<FDIM><<<(ND + 63) / 64, 256, 0, stream>>>(da, pdW1, db1, h1, ND, 1, nullptr);
    gemm_mfma<HDIM><<<(ND + 63) / 64, 256, 0, stream>>>(h1, pdW2, db2, h2, ND, 1, nullptr);
    gin_aggregate<HDIM><<<ND, 64, 0, stream>>>(h2, d_rowptr, d_csrsrc, h3);
    gemm_mfma<HDIM><<<(ND + 63) / 64, 256, 0, stream>>>(h3, pdW3, db3, h1, ND, 1, nullptr);
    gemm_mfma<HDIM><<<(ND + 63) / 64, 256, 0, stream>>>(h1, pdW4, db4, h3, ND, 0, pooled + 256);

    // ---- head ----
    mlp_head<<<1, 256, 0, stream>>>(pooled, lW1, lb1, lW2, lb2, lW3, lb3, (float*)d_out);
}

// Round 5
// 305.250 us; speedup vs baseline: 4.7147x; 1.6085x over previous
//
#include <hip/hip_runtime.h>
#include <hip/hip_bf16.h>

// ---------------------------------------------------------------------------
// BasicCountNet round 5:
//   - bf16 activations end-to-end: x converted once; aggregation gathers bf16
//     rows (fp32 accumulate); GEMM stages bf16 A directly; C stored bf16.
//   - final GEMM stores no C (pool-only epilogue).
//   - dual kernels (data+query in one launch) + single pack kernel: 17
//     dispatches total.
// ---------------------------------------------------------------------------

#define NQ 64
#define EQ 512
#define ND 50000
#define ED 600000
#define FDIM 128
#define HDIM 256

typedef __attribute__((ext_vector_type(8))) short short8;
typedef __attribute__((ext_vector_type(4))) float f32x4;
typedef __attribute__((ext_vector_type(4))) unsigned short us4;
typedef __attribute__((ext_vector_type(2))) unsigned short us2;

__device__ __forceinline__ unsigned short f2bf(float f) {
    union { float f; unsigned u; } v; v.f = f;
    unsigned r = v.u + 0x7FFF + ((v.u >> 16) & 1);   // RNE
    return (unsigned short)(r >> 16);
}
__device__ __forceinline__ float bf2f(unsigned short u) {
    union { unsigned u; float f; } v; v.u = ((unsigned)u) << 16;
    return v.f;
}

// ---------------- fp32 -> bf16 conversion (both inputs, adjacent dests) ----------------

__global__ void cvt_to_bf16(const float* __restrict__ xd, const float* __restrict__ xq,
                            unsigned short* __restrict__ out, long long nd4, long long n4) {
    long long i = (long long)blockIdx.x * 256 + threadIdx.x;
    if (i >= n4) return;
    const float* src = (i < nd4) ? (xd + i * 4) : (xq + (i - nd4) * 4);
    float4 v = *(const float4*)src;
    us4 o;
    o[0] = f2bf(v.x); o[1] = f2bf(v.y); o[2] = f2bf(v.z); o[3] = f2bf(v.w);
    *(us4*)(out + i * 4) = o;
}

// ---------------- CSR build (dual: data blocks then query blocks) ----------------

__global__ void count_deg_both(const int* __restrict__ d_dst, int* __restrict__ d_deg,
                               const int* __restrict__ q_dst, int* __restrict__ q_deg,
                               int dblocks) {
    int b = blockIdx.x;
    if (b < dblocks) {
        int e = b * 256 + threadIdx.x;
        if (e < ED) atomicAdd(&d_deg[d_dst[e]], 1);
    } else {
        int e = (b - dblocks) * 256 + threadIdx.x;
        if (e < EQ) atomicAdd(&q_deg[q_dst[e]], 1);
    }
}

__device__ __forceinline__ void scan1_body(const int* deg, int* rowptr, int* bsum,
                                           int n, int blk) {
    __shared__ int sh[256];
    const int t = threadIdx.x;
    const int i = blk * 256 + t;
    const int v = (i < n) ? deg[i] : 0;
    sh[t] = v;
    __syncthreads();
    for (int off = 1; off < 256; off <<= 1) {
        int x = (t >= off) ? sh[t - off] : 0;
        __syncthreads();
        sh[t] += x;
        __syncthreads();
    }
    if (i < n) rowptr[i] = sh[t] - v;
    if (t == 255) bsum[blk] = sh[255];
}

__global__ void scan_phase1_both(const int* __restrict__ d_deg, int* __restrict__ d_rowptr,
                                 int* __restrict__ d_bsum,
                                 const int* __restrict__ q_deg, int* __restrict__ q_rowptr,
                                 int* __restrict__ q_bsum, int dblocks) {
    int b = blockIdx.x;
    if (b < dblocks) scan1_body(d_deg, d_rowptr, d_bsum, ND, b);
    else             scan1_body(q_deg, q_rowptr, q_bsum, NQ, b - dblocks);
}

__device__ __forceinline__ void scan2_body(const int* bsum, int* boff, int* rowptr_n, int nb) {
    __shared__ int sh[256];
    const int t = threadIdx.x;
    const int v = (t < nb) ? bsum[t] : 0;
    sh[t] = v;
    __syncthreads();
    for (int off = 1; off < 256; off <<= 1) {
        int x = (t >= off) ? sh[t - off] : 0;
        __syncthreads();
        sh[t] += x;
        __syncthreads();
    }
    if (t < nb) boff[t] = sh[t] - v;
    if (t == 255) *rowptr_n = sh[255];
}

__global__ void scan_phase2_both(const int* __restrict__ d_bsum, int* __restrict__ d_boff,
                                 int* __restrict__ d_rowptr_n, int d_nb,
                                 const int* __restrict__ q_bsum, int* __restrict__ q_boff,
                                 int* __restrict__ q_rowptr_n, int q_nb) {
    if (blockIdx.x == 0) scan2_body(d_bsum, d_boff, d_rowptr_n, d_nb);
    else                 scan2_body(q_bsum, q_boff, q_rowptr_n, q_nb);
}

__global__ void scan_phase3_both(int* __restrict__ d_rowptr, const int* __restrict__ d_boff,
                                 int* __restrict__ d_cursor,
                                 int* __restrict__ q_rowptr, const int* __restrict__ q_boff,
                                 int* __restrict__ q_cursor, int dblocks) {
    int b = blockIdx.x;
    if (b < dblocks) {
        int i = b * 256 + threadIdx.x;
        if (i < ND) {
            int r = d_rowptr[i] + d_boff[b];
            d_rowptr[i] = r; d_cursor[i] = r;
        }
    } else {
        int i = (b - dblocks) * 256 + threadIdx.x;
        if (i < NQ) {
            int r = q_rowptr[i] + q_boff[b - dblocks];
            q_rowptr[i] = r; q_cursor[i] = r;
        }
    }
}

__global__ void fill_csr_both(const int* __restrict__ d_src, const int* __restrict__ d_dst,
                              int* __restrict__ d_cursor, int* __restrict__ d_csrsrc,
                              const int* __restrict__ q_src, const int* __restrict__ q_dst,
                              int* __restrict__ q_cursor, int* __restrict__ q_csrsrc,
                              int dblocks) {
    int b = blockIdx.x;
    if (b < dblocks) {
        int e = b * 256 + threadIdx.x;
        if (e < ED) {
            int p = atomicAdd(&d_cursor[d_dst[e]], 1);
            d_csrsrc[p] = d_src[e];
        }
    } else {
        int e = (b - dblocks) * 256 + threadIdx.x;
        if (e < EQ) {
            int p = atomicAdd(&q_cursor[q_dst[e]], 1);
            q_csrsrc[p] = q_src[e];
        }
    }
}

// ---------------- aggregation (bf16 in / bf16 out, fp32 accumulate) ----------------
// out[n] = x[n] + sum_{j in N(n)} x[j];  dual: data nodes then query nodes

template <int F>
__global__ void gin_agg_dual(const unsigned short* __restrict__ xd, const int* __restrict__ rpd,
                             const int* __restrict__ csd, unsigned short* __restrict__ od,
                             const unsigned short* __restrict__ xq, const int* __restrict__ rpq,
                             const int* __restrict__ csq, unsigned short* __restrict__ oq) {
    constexpr int V = F / 64;  // 4 (F=256) or 2 (F=128)
    const unsigned short* x; const int* rowptr; const int* csr; unsigned short* out; int node;
    if ((int)blockIdx.x < ND) { x = xd; rowptr = rpd; csr = csd; out = od; node = blockIdx.x; }
    else { x = xq; rowptr = rpq; csr = csq; out = oq; node = blockIdx.x - ND; }

    const int t = threadIdx.x;  // 0..63
    const int beg = rowptr[node];
    const int end = rowptr[node + 1];

    float acc[V];
    {
        const unsigned short* p = x + (size_t)node * F + t * V;
        if constexpr (V == 4) {
            us4 v = *(const us4*)p;
#pragma unroll
            for (int i = 0; i < 4; ++i) acc[i] = bf2f(v[i]);
        } else {
            us2 v = *(const us2*)p;
            acc[0] = bf2f(v[0]); acc[1] = bf2f(v[1]);
        }
    }
    int j = beg;
    for (; j + 1 < end; j += 2) {
        const unsigned short* p0 = x + (size_t)csr[j] * F + t * V;
        const unsigned short* p1 = x + (size_t)csr[j + 1] * F + t * V;
        if constexpr (V == 4) {
            us4 v0 = *(const us4*)p0;
            us4 v1 = *(const us4*)p1;
#pragma unroll
            for (int i = 0; i < 4; ++i) acc[i] += bf2f(v0[i]) + bf2f(v1[i]);
        } else {
            us2 v0 = *(const us2*)p0;
            us2 v1 = *(const us2*)p1;
            acc[0] += bf2f(v0[0]) + bf2f(v1[0]);
            acc[1] += bf2f(v0[1]) + bf2f(v1[1]);
        }
    }
    if (j < end) {
        const unsigned short* p0 = x + (size_t)csr[j] * F + t * V;
        if constexpr (V == 4) {
            us4 v0 = *(const us4*)p0;
#pragma unroll
            for (int i = 0; i < 4; ++i) acc[i] += bf2f(v0[i]);
        } else {
            us2 v0 = *(const us2*)p0;
            acc[0] += bf2f(v0[0]); acc[1] += bf2f(v0[1]);
        }
    }
    unsigned short* po = out + (size_t)node * F + t * V;
    if constexpr (V == 4) {
        us4 r;
#pragma unroll
        for (int i = 0; i < 4; ++i) r[i] = f2bf(acc[i]);
        *(us4*)po = r;
    } else {
        us2 r; r[0] = f2bf(acc[0]); r[1] = f2bf(acc[1]);
        *(us2*)po = r;
    }
}

// ---------------- weight packing: all 8 matrices, one launch ----------------
// Wp layout: [ct(16)][kt(KT)][lane(64)][j(8)]; elem = W[kt*32+(l>>4)*8+j][ct*16+(l&15)]

struct PackDesc {
    const float* W[8];
    unsigned short* Wp[8];
    int KT[8];
    int start[9];
};

__global__ void pack_all(PackDesc pd) {
    int b = blockIdx.x;
    int m = 0;
    while (m < 7 && b >= pd.start[m + 1]) ++m;
    const int local = b - pd.start[m];
    const int KT = pd.KT[m];
    const int kt = local % KT;
    const int ct = local / KT;
    const float* W = pd.W[m];
    unsigned short* Wp = pd.Wp[m];
    const int l = threadIdx.x;  // 0..63
    const int row = kt * 32 + (l >> 4) * 8;
    const int col = ct * 16 + (l & 15);
    short8 v;
#pragma unroll
    for (int j = 0; j < 8; ++j) v[j] = (short)f2bf(W[(size_t)(row + j) * 256 + col]);
    *(short8*)(Wp + (((size_t)(ct * KT + kt)) * 64 + l) * 8) = v;
}

// ---------------- GEMM: C[N,256] = act(A[N,K] @ W[K,256] + b), bf16 A/C ----------------
// dual: data blocks [0,ndb) then 1 query block. C==null -> pool-only epilogue.

template <int K>
__global__ __launch_bounds__(256) void gemm_dual(
    const unsigned short* __restrict__ Ad, const unsigned short* __restrict__ Wpd,
    const float* __restrict__ bd, unsigned short* __restrict__ Cd, int Nd, int ndb,
    const unsigned short* __restrict__ Aq, const unsigned short* __restrict__ Wpq,
    const float* __restrict__ bq, unsigned short* __restrict__ Cq,
    float* __restrict__ poold, float* __restrict__ poolq, int relu) {
    constexpr int KT = K / 32;
    __shared__ __align__(16) unsigned short As[64 * K];  // bf16, XOR-swizzled

    const unsigned short* A; const unsigned short* Wp; const float* bias;
    unsigned short* C; float* pool; int row0, N;
    if ((int)blockIdx.x < ndb) {
        A = Ad; Wp = Wpd; bias = bd; C = Cd; pool = poold;
        row0 = blockIdx.x * 64; N = Nd;
    } else {
        A = Aq; Wp = Wpq; bias = bq; C = Cq; pool = poolq;
        row0 = 0; N = NQ;
    }
    const int tid = threadIdx.x;
    const int nrows = (N - row0 < 64) ? (N - row0) : 64;

    // stage A (already bf16): swizzled 16B copies
    for (int idx = tid; idx < nrows * (K / 8); idx += 256) {
        const int r = idx / (K / 8);
        const int k8 = (idx % (K / 8)) * 8;
        short8 v = *(const short8*)(A + (size_t)(row0 + r) * K + k8);
        unsigned byte = (unsigned)(r * K + k8) * 2;
        byte ^= (unsigned)((r & 7) << 4);
        *(short8*)((char*)As + byte) = v;
    }
    __syncthreads();

    const int lane = tid & 63;
    const int wv = tid >> 6;        // wave id: cols wv*64..+63
    const int lrow = lane & 15;
    const int lk2 = (lane >> 4) * 8;

    f32x4 acc[4][4];
#pragma unroll
    for (int fm = 0; fm < 4; ++fm)
#pragma unroll
        for (int fn = 0; fn < 4; ++fn) acc[fm][fn] = (f32x4)(0.f);

    const unsigned short* WpBase = Wp + ((size_t)(wv * 4) * KT * 64 + lane) * 8;

    for (int kt = 0; kt < KT; ++kt) {
        short8 a[4], bf[4];
#pragma unroll
        for (int fm = 0; fm < 4; ++fm) {
            const int r = fm * 16 + lrow;
            unsigned byte = (unsigned)(r * K + kt * 32 + lk2) * 2;
            byte ^= (unsigned)((r & 7) << 4);
            a[fm] = *(const short8*)((const char*)As + byte);
        }
#pragma unroll
        for (int fn = 0; fn < 4; ++fn)
            bf[fn] = *(const short8*)(WpBase + ((size_t)fn * KT + kt) * 64 * 8);
#pragma unroll
        for (int fm = 0; fm < 4; ++fm)
#pragma unroll
            for (int fn = 0; fn < 4; ++fn)
                acc[fm][fn] = __builtin_amdgcn_mfma_f32_16x16x32_bf16(
                    a[fm], bf[fn], acc[fm][fn], 0, 0, 0);
    }

    // epilogue: C/D mapping col=lane&15, row=(lane>>4)*4+reg  [m89]
#pragma unroll
    for (int fn = 0; fn < 4; ++fn) {
        const int col = wv * 64 + fn * 16 + lrow;
        const float bv = bias[col];
        float ps = 0.f;
#pragma unroll
        for (int fm = 0; fm < 4; ++fm) {
            const int rbase = row0 + fm * 16 + (lane >> 4) * 4;
#pragma unroll
            for (int r = 0; r < 4; ++r) {
                const int row = rbase + r;
                if (row < N) {
                    float v = acc[fm][fn][r] + bv;
                    if (relu) v = fmaxf(v, 0.f);
                    if (C) C[(size_t)row * 256 + col] = f2bf(v);
                    ps += v;
                }
            }
        }
        if (pool) {
            ps += __shfl_xor(ps, 16);
            ps += __shfl_xor(ps, 32);
            if ((lane >> 4) == 0) atomicAdd(&pool[col], ps);
        }
    }
}

// ---------------- head ----------------

__global__ void mlp_head(const float* __restrict__ pooled,
                         const float* __restrict__ lW1, const float* __restrict__ lb1,
                         const float* __restrict__ lW2, const float* __restrict__ lb2,
                         const float* __restrict__ lW3, const float* __restrict__ lb3,
                         float* __restrict__ out) {
    __shared__ float h0[512];
    __shared__ float h1[256];
    __shared__ float h2[128];
    const int t = threadIdx.x;  // 256 threads
    h0[t] = pooled[t];
    h0[t + 256] = pooled[t + 256];
    __syncthreads();

    float acc = lb1[t];
    for (int k = 0; k < 512; ++k) acc += h0[k] * lW1[k * 256 + t];
    h1[t] = fmaxf(acc, 0.f);
    __syncthreads();

    if (t < 128) {
        float a = lb2[t];
        for (int k = 0; k < 256; ++k) a += h1[k] * lW2[k * 128 + t];
        h2[t] = fmaxf(a, 0.f);
    }
    __syncthreads();

    if (t < 8) {
        float a = lb3[t];
        for (int k = 0; k < 128; ++k) a += h2[k] * lW3[k * 8 + t];
        out[t] = fmaxf(a, 0.f);
    }
}

// ---------------------------------------------------------------------------

extern "C" void kernel_launch(void* const* d_in, const int* in_sizes, int n_in,
                              void* d_out, int out_size, void* d_ws, size_t ws_size,
                              hipStream_t stream) {
    const float* q_x  = (const float*)d_in[0];
    const float* d_x  = (const float*)d_in[1];
    const int*   q_el = (const int*)d_in[2];
    const int*   d_el = (const int*)d_in[3];
    const float* qW1 = (const float*)d_in[4];  const float* qb1 = (const float*)d_in[5];
    const float* qW2 = (const float*)d_in[6];  const float* qb2 = (const float*)d_in[7];
    const float* qW3 = (const float*)d_in[8];  const float* qb3 = (const float*)d_in[9];
    const float* qW4 = (const float*)d_in[10]; const float* qb4 = (const float*)d_in[11];
    const float* dW1 = (const float*)d_in[12]; const float* db1 = (const float*)d_in[13];
    const float* dW2 = (const float*)d_in[14]; const float* db2 = (const float*)d_in[15];
    const float* dW3 = (const float*)d_in[16]; const float* db3 = (const float*)d_in[17];
    const float* dW4 = (const float*)d_in[18]; const float* db4 = (const float*)d_in[19];
    const float* lW1 = (const float*)d_in[20]; const float* lb1 = (const float*)d_in[21];
    const float* lW2 = (const float*)d_in[22]; const float* lb2 = (const float*)d_in[23];
    const float* lW3 = (const float*)d_in[24]; const float* lb3 = (const float*)d_in[25];
    (void)in_sizes; (void)n_in; (void)out_size; (void)ws_size;

    const int* q_src = q_el;  const int* q_dst = q_el + EQ;
    const int* d_src = d_el;  const int* d_dst = d_el + ED;

    // ---- workspace layout ----
    char* wsb = (char*)d_ws;
    size_t off = 0;
    auto alloc = [&](size_t bytes) { void* p = wsb + off; off += (bytes + 255) & ~(size_t)255; return p; };

    unsigned short* bxd = (unsigned short*)alloc((size_t)ND * FDIM * 2);  // bf16 d_x
    unsigned short* bxq = (unsigned short*)alloc((size_t)NQ * FDIM * 2);  // bf16 q_x (adjacent!)
    unsigned short* da  = (unsigned short*)alloc((size_t)ND * FDIM * 2);
    unsigned short* h1  = (unsigned short*)alloc((size_t)ND * HDIM * 2);
    unsigned short* h2  = (unsigned short*)alloc((size_t)ND * HDIM * 2);
    unsigned short* h3  = (unsigned short*)alloc((size_t)ND * HDIM * 2);
    unsigned short* qa  = (unsigned short*)alloc((size_t)NQ * FDIM * 2);
    unsigned short* k1  = (unsigned short*)alloc((size_t)NQ * HDIM * 2);
    unsigned short* k2  = (unsigned short*)alloc((size_t)NQ * HDIM * 2);
    unsigned short* k3  = (unsigned short*)alloc((size_t)NQ * HDIM * 2);
    float* pooled = (float*)alloc(512 * 4);
    int* d_deg    = (int*)alloc((size_t)ND * 4);
    int* q_deg    = (int*)alloc((size_t)NQ * 4);   // adjacent to d_deg for one memset
    int* d_rowptr = (int*)alloc((size_t)(ND + 1) * 4);
    int* d_cursor = (int*)alloc((size_t)ND * 4);
    int* d_csrsrc = (int*)alloc((size_t)ED * 4);
    int* d_bsum   = (int*)alloc(256 * 4);
    int* d_boff   = (int*)alloc(256 * 4);
    int* q_rowptr = (int*)alloc((size_t)(NQ + 1) * 4);
    int* q_cursor = (int*)alloc((size_t)NQ * 4);
    int* q_csrsrc = (int*)alloc((size_t)EQ * 4);
    int* q_bsum   = (int*)alloc(256 * 4);
    int* q_boff   = (int*)alloc(256 * 4);
    unsigned short* pdW1 = (unsigned short*)alloc((size_t)FDIM * 256 * 2);
    unsigned short* pdW2 = (unsigned short*)alloc((size_t)HDIM * 256 * 2);
    unsigned short* pdW3 = (unsigned short*)alloc((size_t)HDIM * 256 * 2);
    unsigned short* pdW4 = (unsigned short*)alloc((size_t)HDIM * 256 * 2);
    unsigned short* pqW1 = (unsigned short*)alloc((size_t)FDIM * 256 * 2);
    unsigned short* pqW2 = (unsigned short*)alloc((size_t)HDIM * 256 * 2);
    unsigned short* pqW3 = (unsigned short*)alloc((size_t)HDIM * 256 * 2);
    unsigned short* pqW4 = (unsigned short*)alloc((size_t)HDIM * 256 * 2);

    hipMemsetAsync(pooled, 0, 512 * 4, stream);
    hipMemsetAsync(d_deg, 0, (char*)(q_deg + NQ) - (char*)d_deg, stream);

    // ---- input conversion ----
    {
        long long nd4 = (long long)ND * FDIM / 4;
        long long n4 = nd4 + (long long)NQ * FDIM / 4;
        cvt_to_bf16<<<(int)((n4 + 255) / 256), 256, 0, stream>>>(d_x, q_x, bxd, nd4, n4);
    }

    // ---- weight packing (one launch) ----
    {
        PackDesc pd;
        const float* Ws[8] = {dW1, dW2, dW3, dW4, qW1, qW2, qW3, qW4};
        unsigned short* Wps[8] = {pdW1, pdW2, pdW3, pdW4, pqW1, pqW2, pqW3, pqW4};
        int kts[8] = {4, 8, 8, 8, 4, 8, 8, 8};
        int s = 0;
        for (int i = 0; i < 8; ++i) {
            pd.W[i] = Ws[i]; pd.Wp[i] = Wps[i]; pd.KT[i] = kts[i];
            pd.start[i] = s; s += 16 * kts[i];
        }
        pd.start[8] = s;
        pack_all<<<s, 64, 0, stream>>>(pd);
    }

    // ---- CSR build ----
    const int d_eb = (ED + 255) / 256;   // 2344
    const int q_eb = (EQ + 255) / 256;   // 2
    const int d_nb = (ND + 255) / 256;   // 196
    const int q_nb = (NQ + 255) / 256;   // 1
    count_deg_both<<<d_eb + q_eb, 256, 0, stream>>>(d_dst, d_deg, q_dst, q_deg, d_eb);
    scan_phase1_both<<<d_nb + q_nb, 256, 0, stream>>>(d_deg, d_rowptr, d_bsum,
                                                      q_deg, q_rowptr, q_bsum, d_nb);
    scan_phase2_both<<<2, 256, 0, stream>>>(d_bsum, d_boff, d_rowptr + ND, d_nb,
                                            q_bsum, q_boff, q_rowptr + NQ, q_nb);
    scan_phase3_both<<<d_nb + q_nb, 256, 0, stream>>>(d_rowptr, d_boff, d_cursor,
                                                      q_rowptr, q_boff, q_cursor, d_nb);
    fill_csr_both<<<d_eb + q_eb, 256, 0, stream>>>(d_src, d_dst, d_cursor, d_csrsrc,
                                                   q_src, q_dst, q_cursor, q_csrsrc, d_eb);

    // ---- GIN layers (dual data+query) ----
    const int ndb = (ND + 63) / 64;  // 782

    gin_agg_dual<FDIM><<<ND + NQ, 64, 0, stream>>>(bxd, d_rowptr, d_csrsrc, da,
                                                   bxq, q_rowptr, q_csrsrc, qa);
    gemm_dual<FDIM><<<ndb + 1, 256, 0, stream>>>(da, pdW1, db1, h1, ND, ndb,
                                                 qa, pqW1, qb1, k1,
                                                 nullptr, nullptr, 1);
    gemm_dual<HDIM><<<ndb + 1, 256, 0, stream>>>(h1, pdW2, db2, h2, ND, ndb,
                                                 k1, pqW2, qb2, k2,
                                                 nullptr, nullptr, 1);  // inter-conv ReLU fused
    gin_agg_dual<HDIM><<<ND + NQ, 64, 0, stream>>>(h2, d_rowptr, d_csrsrc, h3,
                                                   k2, q_rowptr, q_csrsrc, k3);
    gemm_dual<HDIM><<<ndb + 1, 256, 0, stream>>>(h3, pdW3, db3, h1, ND, ndb,
                                                 k3, pqW3, qb3, k1,
                                                 nullptr, nullptr, 1);
    gemm_dual<HDIM><<<ndb + 1, 256, 0, stream>>>(h1, pdW4, db4, nullptr, ND, ndb,
                                                 k1, pqW4, qb4, nullptr,
                                                 pooled + 256, pooled, 0);  // pool-only

    // ---- head ----
    mlp_head<<<1, 256, 0, stream>>>(pooled, lW1, lb1, lW2, lb2, lW3, lb3, (float*)d_out);
}